// Round 6
// baseline (423.813 us; speedup 1.0000x reference)
//
#include <hip/hip_runtime.h>
#include <climits>

typedef __attribute__((ext_vector_type(8))) short s8;      // 8 bf16 = 4 VGPRs
typedef __attribute__((ext_vector_type(4))) float f32x4;   // MFMA acc

#define BQ    256
#define DDIM  256
#define NBANK 100000
#define BN    64                          // bank cols per chunk (4 col-tiles of 16)
#define GRIDX 782                         // chunks: GRIDX*2 = 1564 >= 1563
#define SSTR  258                         // 16B-slot stride per slice (write-swizzle pad)
#define INIT64 0xFFFFFFFFFFFFFFFFULL

__device__ inline void splitElem(float x, s8& h, s8& l, int i) {
    unsigned u  = __float_as_uint(x);
    unsigned uh = (u + 0x8000u) & 0xFFFF0000u;
    h[i] = (short)(uh >> 16);
    float lf = x - __uint_as_float(uh);            // exact
    l[i] = (short)((__float_as_uint(lf) + 0x8000u) >> 16);
}

__device__ inline void split8(const float4 v0, const float4 v1, s8& h, s8& l) {
    splitElem(v0.x, h, l, 0); splitElem(v0.y, h, l, 1);
    splitElem(v0.z, h, l, 2); splitElem(v0.w, h, l, 3);
    splitElem(v1.x, h, l, 4); splitElem(v1.y, h, l, 5);
    splitElem(v1.z, h, l, 6); splitElem(v1.w, h, l, 7);
}

__device__ inline float sq8(const float4 v0, const float4 v1, float s) {
    s = fmaf(v0.x, v0.x, s); s = fmaf(v0.y, v0.y, s);
    s = fmaf(v0.z, v0.z, s); s = fmaf(v0.w, v0.w, s);
    s = fmaf(v1.x, v1.x, s); s = fmaf(v1.y, v1.y, s);
    s = fmaf(v1.z, v1.z, s); s = fmaf(v1.w, v1.w, s);
    return s;
}

// Monotone fp32->u32, packed with index: u64 min == (min val, then min idx). Exact.
__device__ inline unsigned long long packMin(float v, int idx) {
    unsigned b = __float_as_uint(v);
    unsigned u = (b & 0x80000000u) ? ~b : (b | 0x80000000u);
    return ((unsigned long long)u << 32) | (unsigned)idx;
}

__device__ inline unsigned long long shflxor64(unsigned long long x, int m) {
    unsigned lo = (unsigned)x, hi = (unsigned)(x >> 32);
    lo = __shfl_xor(lo, m); hi = __shfl_xor(hi, m);
    return ((unsigned long long)hi << 32) | lo;
}

// Kernel 0: blocks 0-15 split A into MFMA-A-fragment order (RT 0..15, slice 0..7);
// block 16 inits the 512 atomic argmin slots.
__global__ __launch_bounds__(512) void prep(
    const float* __restrict__ feature, s8* __restrict__ fH, s8* __restrict__ fL,
    unsigned long long* __restrict__ slots)
{
    if (blockIdx.x == 16) { slots[threadIdx.x] = INIT64; return; }
    const int t    = blockIdx.x * 512 + threadIdx.x;   // 0..8191
    const int lane = t & 63, ks = (t >> 6) & 7, rt = t >> 9;
    const int row  = rt * 16 + (lane & 15);
    const int k0   = ks * 32 + (lane >> 4) * 8;
    const float* p = feature + (size_t)row * DDIM + k0;
    const float4 v0 = *(const float4*)p;
    const float4 v1 = *(const float4*)(p + 4);
    s8 h, l;
    split8(v0, v1, h, l);
    fH[t] = h; fL[t] = l;
}

// Kernel 1: split-bf16 MFMA GEMM + fused masked argmin (packed atomicMin slots).
// Grid (GRIDX, 2): y = row half (128 rows), x covers 2 col-chunks of 64.
// 256 thr = 4 waves, wave owns 32 rows (rt=0,1). Pipeline per half-K slice-set:
// split->LDS / barrier / issue-next-loads + MFMA compute / barrier.
__global__ __launch_bounds__(256, 3) void gemm_argmin(
    const s8* __restrict__ fH, const s8* __restrict__ fL,
    const float* __restrict__ bank,
    const int* __restrict__ cluster_label, const int* __restrict__ class_label,
    const int* __restrict__ cluster_idx,  const int* __restrict__ gt_label,
    unsigned long long* __restrict__ slots)
{
    __shared__ __align__(16) s8 bHs[4 * SSTR];   // ~16.5 KB (4 slices, swizzle stride)
    __shared__ __align__(16) s8 bLs[4 * SSTR];   // ~16.5 KB
    __shared__ float b2s[BN];
    __shared__ int clsS[BN], cluS[BN], rowGt[128], rowClu[128];

    const int tid  = threadIdx.x;
    const int Y    = blockIdx.y;
    const int row0 = Y * 128;

    if (tid < 128) {
        rowGt[tid]  = gt_label[row0 + tid];
        rowClu[tid] = cluster_idx[row0 + tid];
    }

    // staging role: col 0..63, q = k-slice (of current half) 0..3
    const int col = tid >> 2, q = tid & 3;
    const int ct_s = col >> 4, c_s = col & 15;
    // compute role
    const int w = tid >> 6, lane = tid & 63;
    const int g = lane >> 4, c = lane & 15;
    const int RT0 = Y * 8 + w * 2, RT1 = RT0 + 1;

    f32x4 acc[4][2];
    #pragma unroll
    for (int ct = 0; ct < 4; ++ct) { acc[ct][0] = (f32x4){0,0,0,0}; acc[ct][1] = (f32x4){0,0,0,0}; }
    float sqacc = 0.f;

    const int cc0 = blockIdx.x * 2;
    float4 v[8], p[8];
    {   // preload chunk0, half0: thread's 32 k-floats of slice q
        const int jc = min(cc0 * BN + col, NBANK - 1);
        const float* gp = bank + (size_t)jc * DDIM + q * 32;
        #pragma unroll
        for (int j = 0; j < 8; ++j) v[j] = *(const float4*)(gp + 4 * j);
    }

    for (int ci = 0; ci < 2; ++ci) {
        const int cc = cc0 + ci;
        #pragma unroll
        for (int h = 0; h < 2; ++h) {
            // ---- split current regs -> LDS (frag layout, slice q of this half)
            if (h == 0 && tid < BN) {
                const int jc = min(cc * BN + tid, NBANK - 1);
                clsS[tid] = class_label[jc];
                cluS[tid] = cluster_label[jc];
            }
            #pragma unroll
            for (int g2 = 0; g2 < 4; ++g2) {
                s8 hh, ll;
                split8(v[2 * g2], v[2 * g2 + 1], hh, ll);
                sqacc = sq8(v[2 * g2], v[2 * g2 + 1], sqacc);
                const int wi = q * SSTR + ct_s * 64 + g2 * 16 + c_s;
                bHs[wi] = hh; bLs[wi] = ll;
            }
            if (h == 1) {                      // ||b||^2 complete for this chunk
                float sv = sqacc;
                sv += __shfl_xor(sv, 1);
                sv += __shfl_xor(sv, 2);
                if (q == 0) b2s[col] = sv;
                sqacc = 0.f;
            }
            __syncthreads();

            // ---- issue next (chunk,half) global loads (in flight across compute)
            const bool last = (ci == 1) && (h == 1);
            if (!last) {
                const int nci = (h == 0) ? ci : ci + 1;
                const int nh  = (h == 0) ? 1 : 0;
                const int jc  = min((cc0 + nci) * BN + col, NBANK - 1);
                const float* gp = bank + (size_t)jc * DDIM + nh * 128 + q * 32;
                #pragma unroll
                for (int j = 0; j < 8; ++j) p[j] = *(const float4*)(gp + 4 * j);
            }

            // ---- compute this half: slices s = h*4 + s4
            #pragma unroll
            for (int s4 = 0; s4 < 4; ++s4) {
                const int s = h * 4 + s4;
                const s8 a0H = fH[(RT0 * 8 + s) * 64 + lane];
                const s8 a0L = fL[(RT0 * 8 + s) * 64 + lane];
                const s8 a1H = fH[(RT1 * 8 + s) * 64 + lane];
                const s8 a1L = fL[(RT1 * 8 + s) * 64 + lane];
                #pragma unroll
                for (int ct = 0; ct < 4; ++ct) {
                    const s8 bh = bHs[s4 * SSTR + ct * 64 + lane];
                    const s8 bl = bLs[s4 * SSTR + ct * 64 + lane];
                    acc[ct][0] = __builtin_amdgcn_mfma_f32_16x16x32_bf16(a0H, bh, acc[ct][0], 0, 0, 0);
                    acc[ct][0] = __builtin_amdgcn_mfma_f32_16x16x32_bf16(a0H, bl, acc[ct][0], 0, 0, 0);
                    acc[ct][0] = __builtin_amdgcn_mfma_f32_16x16x32_bf16(a0L, bh, acc[ct][0], 0, 0, 0);
                    acc[ct][0] = __builtin_amdgcn_mfma_f32_16x16x32_bf16(a0L, bl, acc[ct][0], 0, 0, 0);
                    acc[ct][1] = __builtin_amdgcn_mfma_f32_16x16x32_bf16(a1H, bh, acc[ct][1], 0, 0, 0);
                    acc[ct][1] = __builtin_amdgcn_mfma_f32_16x16x32_bf16(a1H, bl, acc[ct][1], 0, 0, 0);
                    acc[ct][1] = __builtin_amdgcn_mfma_f32_16x16x32_bf16(a1L, bh, acc[ct][1], 0, 0, 0);
                    acc[ct][1] = __builtin_amdgcn_mfma_f32_16x16x32_bf16(a1L, bl, acc[ct][1], 0, 0, 0);
                }
            }

            // ---- chunk done: fused masked argmin epilogue (u64-packed, tie-exact)
            if (h == 1) {
                #pragma unroll
                for (int rt = 0; rt < 2; ++rt) {
                    #pragma unroll
                    for (int r = 0; r < 4; ++r) {
                        const int lrow = w * 32 + rt * 16 + g * 4 + r;
                        const int myGt = rowGt[lrow], myClu = rowClu[lrow];
                        unsigned long long pkP = INIT64, pkD = INIT64;
                        #pragma unroll
                        for (int ct = 0; ct < 4; ++ct) {
                            const int jl = ct * 16 + c;
                            const int jg = cc * BN + jl;
                            const float sc = fmaf(-2.f, acc[ct][rt][r], b2s[jl]);
                            if (jg < NBANK && clsS[jl] != myGt) {
                                const unsigned long long pk = packMin(sc, jg);
                                if (pk < pkD) pkD = pk;
                                if (cluS[jl] == myClu && pk < pkP) pkP = pk;
                            }
                        }
                        #pragma unroll
                        for (int off = 1; off < 16; off <<= 1) {
                            unsigned long long t0 = shflxor64(pkP, off);
                            if (t0 < pkP) pkP = t0;
                            t0 = shflxor64(pkD, off);
                            if (t0 < pkD) pkD = t0;
                        }
                        if (c == 0) {
                            const int gr = row0 + lrow;
                            if (pkP != INIT64) {
                                unsigned long long cur = *(const volatile unsigned long long*)(slots + gr);
                                if (pkP < cur) atomicMin(slots + gr, pkP);
                            }
                            if (pkD != INIT64) {
                                unsigned long long cur = *(const volatile unsigned long long*)(slots + 256 + gr);
                                if (pkD < cur) atomicMin(slots + 256 + gr, pkD);
                            }
                        }
                        acc[0][rt][r] = 0.f;   // partial reset folded here
                    }
                }
                #pragma unroll
                for (int ct = 1; ct < 4; ++ct) { acc[ct][0] = (f32x4){0,0,0,0}; acc[ct][1] = (f32x4){0,0,0,0}; }
                #pragma unroll
                for (int r = 0; r < 4; ++r) { acc[0][0][r] = 0.f; acc[0][1][r] = 0.f; }
            }

            if (!last) {
                __syncthreads();               // LDS consumers done before next split
                #pragma unroll
                for (int j = 0; j < 8; ++j) v[j] = p[j];
            }
        }
    }
}

// Kernel 2: decode slots (primary else fallback), gather bank row.
__global__ __launch_bounds__(256) void gather(
    const unsigned long long* __restrict__ slots,
    const float* __restrict__ bank, float* __restrict__ out)
{
    const int row = blockIdx.x, t = threadIdx.x;
    __shared__ int sIdx;
    if (t == 0) {
        unsigned long long p = slots[row];
        unsigned long long d = slots[256 + row];
        unsigned long long chosen = (p != INIT64) ? p : d;
        sIdx = (chosen != INIT64) ? (int)(unsigned)(chosen & 0xFFFFFFFFu) : 0;
    }
    __syncthreads();
    out[row * DDIM + t] = bank[(size_t)sIdx * DDIM + t];
}

extern "C" void kernel_launch(void* const* d_in, const int* in_sizes, int n_in,
                              void* d_out, int out_size, void* d_ws, size_t ws_size,
                              hipStream_t stream) {
    const float* feature       = (const float*)d_in[0];
    const float* bank          = (const float*)d_in[1];
    const int*   cluster_label = (const int*)d_in[2];
    const int*   class_label   = (const int*)d_in[3];
    const int*   cluster_idx   = (const int*)d_in[4];
    const int*   gt_label      = (const int*)d_in[5];
    float* out = (float*)d_out;

    s8* fH = (s8*)d_ws;                 // 8192 frags (128 KB)
    s8* fL = fH + 8192;                 // 128 KB
    unsigned long long* slots = (unsigned long long*)(fL + 8192);   // 4 KB

    hipLaunchKernelGGL(prep, dim3(17), dim3(512), 0, stream, feature, fH, fL, slots);
    hipLaunchKernelGGL(gemm_argmin, dim3(GRIDX, 2), dim3(256), 0, stream,
                       fH, fL, bank, cluster_label, class_label, cluster_idx, gt_label,
                       slots);
    hipLaunchKernelGGL(gather, dim3(BQ), dim3(256), 0, stream, slots, bank, out);
}

// Round 7
// 315.960 us; speedup vs baseline: 1.3414x; 1.3414x over previous
//
#include <hip/hip_runtime.h>
#include <climits>

typedef __attribute__((ext_vector_type(8))) short s8;      // 8 bf16 = 4 VGPRs
typedef __attribute__((ext_vector_type(4))) float f32x4;   // MFMA acc

#define BQ    256
#define DDIM  256
#define NBANK 100000
#define BN    64                          // bank cols per block (4 col-tiles of 16)
#define NJB   ((NBANK + BN - 1) / BN)     // 1563
#define INIT64 0xFFFFFFFFFFFFFFFFULL

__device__ inline void splitElem(float x, s8& h, s8& l, int i) {
    unsigned u  = __float_as_uint(x);
    unsigned uh = (u + 0x8000u) & 0xFFFF0000u;
    h[i] = (short)(uh >> 16);
    float lf = x - __uint_as_float(uh);            // exact
    l[i] = (short)((__float_as_uint(lf) + 0x8000u) >> 16);
}

__device__ inline void split8(const float4 v0, const float4 v1, s8& h, s8& l) {
    splitElem(v0.x, h, l, 0); splitElem(v0.y, h, l, 1);
    splitElem(v0.z, h, l, 2); splitElem(v0.w, h, l, 3);
    splitElem(v1.x, h, l, 4); splitElem(v1.y, h, l, 5);
    splitElem(v1.z, h, l, 6); splitElem(v1.w, h, l, 7);
}

__device__ inline float sq8(const float4 v0, const float4 v1, float s) {
    s = fmaf(v0.x, v0.x, s); s = fmaf(v0.y, v0.y, s);
    s = fmaf(v0.z, v0.z, s); s = fmaf(v0.w, v0.w, s);
    s = fmaf(v1.x, v1.x, s); s = fmaf(v1.y, v1.y, s);
    s = fmaf(v1.z, v1.z, s); s = fmaf(v1.w, v1.w, s);
    return s;
}

// Monotone fp32->u32, packed with index: u64 min == (min val, then min idx). Exact.
__device__ inline unsigned long long packMin(float v, int idx) {
    unsigned b = __float_as_uint(v);
    unsigned u = (b & 0x80000000u) ? ~b : (b | 0x80000000u);
    return ((unsigned long long)u << 32) | (unsigned)idx;
}

__device__ inline unsigned long long shflxor64(unsigned long long x, int m) {
    unsigned lo = (unsigned)x, hi = (unsigned)(x >> 32);
    lo = __shfl_xor(lo, m); hi = __shfl_xor(hi, m);
    return ((unsigned long long)hi << 32) | lo;
}

// Kernel 0: blocks 0-15 split A into MFMA-A-fragment order (RT 0..15, slice 0..7);
// block 16 inits the 512 atomic argmin slots.
__global__ __launch_bounds__(512) void prep(
    const float* __restrict__ feature, s8* __restrict__ fH, s8* __restrict__ fL,
    unsigned long long* __restrict__ slots)
{
    if (blockIdx.x == 16) { slots[threadIdx.x] = INIT64; return; }
    const int t    = blockIdx.x * 512 + threadIdx.x;   // 0..8191
    const int lane = t & 63, ks = (t >> 6) & 7, rt = t >> 9;
    const int row  = rt * 16 + (lane & 15);
    const int k0   = ks * 32 + (lane >> 4) * 8;
    const float* p = feature + (size_t)row * DDIM + k0;
    const float4 v0 = *(const float4*)p;
    const float4 v1 = *(const float4*)(p + 4);
    s8 h, l;
    split8(v0, v1, h, l);
    fH[t] = h; fL[t] = l;
}

// Kernel 1: split-bf16 MFMA GEMM + fused masked argmin (packed atomicMin slots).
// 256 thr = 4 waves; wave w owns rows w*64..+63 (4 row-tiles), all 4 col-tiles.
// NO LDS tiles, NO main-loop barriers: B frags loaded straight from global in
// MFMA lane layout and split in-register; A frags pre-split (L2-resident).
// Compiler free to pipeline the fully-unrolled 8-slice loop.
__global__ __launch_bounds__(256, 2) void gemm_argmin(
    const s8* __restrict__ fH, const s8* __restrict__ fL,
    const float* __restrict__ bank,
    const int* __restrict__ cluster_label, const int* __restrict__ class_label,
    const int* __restrict__ cluster_idx,  const int* __restrict__ gt_label,
    unsigned long long* __restrict__ slots)
{
    __shared__ int rowGt[BQ], rowClu[BQ];
    const int tid = threadIdx.x;
    const int jb  = blockIdx.x;
    const int j0  = jb * BN;

    rowGt[tid]  = gt_label[tid];
    rowClu[tid] = cluster_idx[tid];
    __syncthreads();                       // the only barrier

    const int w = tid >> 6, lane = tid & 63;
    const int g = lane >> 4, c = lane & 15;

    // Per-lane column labels and B base pointers (col = j0 + ct*16 + c, clamped)
    int clsR[4], cluR[4];
    const float* bp[4];
    #pragma unroll
    for (int ct = 0; ct < 4; ++ct) {
        const int jc = min(j0 + ct * 16 + c, NBANK - 1);
        clsR[ct] = class_label[jc];
        cluR[ct] = cluster_label[jc];
        bp[ct]   = bank + (size_t)jc * DDIM + g * 8;
    }

    f32x4 acc[4][4];
    #pragma unroll
    for (int ct = 0; ct < 4; ++ct)
        #pragma unroll
        for (int rt = 0; rt < 4; ++rt)
            acc[ct][rt] = (f32x4){0.f, 0.f, 0.f, 0.f};
    float b2a[4] = {0.f, 0.f, 0.f, 0.f};

    #pragma unroll
    for (int s = 0; s < 8; ++s) {
        // B frags: lane (g,c) reads col j0+ct*16+c, k = s*32+g*8..+7 (fp32)
        float4 b0[4], b1[4];
        #pragma unroll
        for (int ct = 0; ct < 4; ++ct) {
            b0[ct] = *(const float4*)(bp[ct] + s * 32);
            b1[ct] = *(const float4*)(bp[ct] + s * 32 + 4);
        }
        // A frags: pre-split, fragment-ordered, L2-resident
        s8 aH[4], aL[4];
        #pragma unroll
        for (int rt = 0; rt < 4; ++rt) {
            aH[rt] = fH[((w * 4 + rt) * 8 + s) * 64 + lane];
            aL[rt] = fL[((w * 4 + rt) * 8 + s) * 64 + lane];
        }
        s8 bh[4], bl[4];
        #pragma unroll
        for (int ct = 0; ct < 4; ++ct) {
            split8(b0[ct], b1[ct], bh[ct], bl[ct]);
            b2a[ct] = sq8(b0[ct], b1[ct], b2a[ct]);
        }
        #pragma unroll
        for (int ct = 0; ct < 4; ++ct)
            #pragma unroll
            for (int rt = 0; rt < 4; ++rt) {
                acc[ct][rt] = __builtin_amdgcn_mfma_f32_16x16x32_bf16(aH[rt], bh[ct], acc[ct][rt], 0, 0, 0);
                acc[ct][rt] = __builtin_amdgcn_mfma_f32_16x16x32_bf16(aH[rt], bl[ct], acc[ct][rt], 0, 0, 0);
                acc[ct][rt] = __builtin_amdgcn_mfma_f32_16x16x32_bf16(aL[rt], bh[ct], acc[ct][rt], 0, 0, 0);
                acc[ct][rt] = __builtin_amdgcn_mfma_f32_16x16x32_bf16(aL[rt], bl[ct], acc[ct][rt], 0, 0, 0);
            }
    }

    // ||b||^2: lane holds octet-g partial for col (ct,c); sum over g (xor 16,32)
    #pragma unroll
    for (int ct = 0; ct < 4; ++ct) {
        b2a[ct] += __shfl_xor(b2a[ct], 16);
        b2a[ct] += __shfl_xor(b2a[ct], 32);
    }

    // Epilogue: C/D layout col=lane&15, row=g*4+reg (HW-verified, absmax 0 R3-R6)
    #pragma unroll
    for (int rt = 0; rt < 4; ++rt) {
        #pragma unroll
        for (int r = 0; r < 4; ++r) {
            const int row  = w * 64 + rt * 16 + g * 4 + r;
            const int myGt = rowGt[row], myClu = rowClu[row];
            unsigned long long pkP = INIT64, pkD = INIT64;
            #pragma unroll
            for (int ct = 0; ct < 4; ++ct) {
                const int jg = j0 + ct * 16 + c;
                const float sc = fmaf(-2.f, acc[ct][rt][r], b2a[ct]);
                if (jg < NBANK && clsR[ct] != myGt) {
                    const unsigned long long pk = packMin(sc, jg);
                    if (pk < pkD) pkD = pk;
                    if (cluR[ct] == myClu && pk < pkP) pkP = pk;
                }
            }
            #pragma unroll
            for (int off = 1; off < 16; off <<= 1) {   // 16-lane group shares this row
                unsigned long long t0 = shflxor64(pkP, off);
                if (t0 < pkP) pkP = t0;
                t0 = shflxor64(pkD, off);
                if (t0 < pkD) pkD = t0;
            }
            if (c == 0) {
                if (pkP != INIT64) {
                    unsigned long long cur = *(const volatile unsigned long long*)(slots + row);
                    if (pkP < cur) atomicMin(slots + row, pkP);
                }
                if (pkD != INIT64) {
                    unsigned long long cur = *(const volatile unsigned long long*)(slots + 256 + row);
                    if (pkD < cur) atomicMin(slots + 256 + row, pkD);
                }
            }
        }
    }
}

// Kernel 2: decode slots (primary else fallback), gather bank row.
__global__ __launch_bounds__(256) void gather(
    const unsigned long long* __restrict__ slots,
    const float* __restrict__ bank, float* __restrict__ out)
{
    const int row = blockIdx.x, t = threadIdx.x;
    __shared__ int sIdx;
    if (t == 0) {
        unsigned long long p = slots[row];
        unsigned long long d = slots[256 + row];
        unsigned long long chosen = (p != INIT64) ? p : d;
        sIdx = (chosen != INIT64) ? (int)(unsigned)(chosen & 0xFFFFFFFFu) : 0;
    }
    __syncthreads();
    out[row * DDIM + t] = bank[(size_t)sIdx * DDIM + t];
}

extern "C" void kernel_launch(void* const* d_in, const int* in_sizes, int n_in,
                              void* d_out, int out_size, void* d_ws, size_t ws_size,
                              hipStream_t stream) {
    const float* feature       = (const float*)d_in[0];
    const float* bank          = (const float*)d_in[1];
    const int*   cluster_label = (const int*)d_in[2];
    const int*   class_label   = (const int*)d_in[3];
    const int*   cluster_idx   = (const int*)d_in[4];
    const int*   gt_label      = (const int*)d_in[5];
    float* out = (float*)d_out;

    s8* fH = (s8*)d_ws;                 // 8192 frags (128 KB)
    s8* fL = fH + 8192;                 // 128 KB
    unsigned long long* slots = (unsigned long long*)(fL + 8192);   // 4 KB

    hipLaunchKernelGGL(prep, dim3(17), dim3(512), 0, stream, feature, fH, fL, slots);
    hipLaunchKernelGGL(gemm_argmin, dim3(NJB), dim3(256), 0, stream,
                       fH, fL, bank, cluster_label, class_label, cluster_idx, gt_label,
                       slots);
    hipLaunchKernelGGL(gather, dim3(BQ), dim3(256), 0, stream, slots, bank, out);
}